// Round 3
// baseline (749.306 us; speedup 1.0000x reference)
//
#include <hip/hip_runtime.h>
#include <hip/hip_bf16.h>

typedef __bf16 bf16;
typedef __attribute__((ext_vector_type(8))) __bf16 bf16x8;
typedef __attribute__((ext_vector_type(4))) float floatx4;

#define BATCH 8192
#define NREC  1024
#define DHID  2048

#define GLOBAL_AS __attribute__((address_space(1)))
#define LDS_AS    __attribute__((address_space(3)))

__device__ __forceinline__ bf16 to_bf16(float f) { return (bf16)f; }

// async global->LDS, 16 bytes per lane; LDS dest = wave-uniform base + lane*16
__device__ __forceinline__ void async16(const void* g, void* l) {
  __builtin_amdgcn_global_load_lds((const GLOBAL_AS unsigned int*)g,
                                   (LDS_AS unsigned int*)l, 16, 0, 0);
}

// raw barrier: no implicit vmcnt/lgkmcnt drain (unlike __syncthreads) -- this is
// what lets staged loads stay in flight across phase boundaries (T4).
#define BAR()                                 \
  do {                                        \
    asm volatile("" ::: "memory");            \
    __builtin_amdgcn_s_barrier();             \
    asm volatile("" ::: "memory");            \
  } while (0)

#define LGKM0()                                            \
  do {                                                     \
    asm volatile("s_waitcnt lgkmcnt(0)" ::: "memory");     \
    __builtin_amdgcn_sched_barrier(0);                     \
  } while (0)

#define VMW(N) asm volatile("s_waitcnt vmcnt(" #N ")" ::: "memory")

// ---------------- prep kernels ----------------

__global__ void lam_kernel(const float* __restrict__ nu, const float* __restrict__ theta,
                           float* __restrict__ lamRe, float* __restrict__ lamIm) {
  int h = blockIdx.x * blockDim.x + threadIdx.x;
  if (h < DHID) {
    float t = expf(-expf(nu[h]));
    lamRe[h] = t * cosf(theta[h]);
    lamIm[h] = t * sinf(theta[h]);
  }
}

// f32 -> bf16, 4 elements/thread
__global__ void convert_kernel(const float* __restrict__ src, bf16* __restrict__ dst) {
  int idx = blockIdx.x * blockDim.x + threadIdx.x;
  float4 v = reinterpret_cast<const float4*>(src)[idx];
  ushort4 pk;
  pk.x = __builtin_bit_cast(unsigned short, to_bf16(v.x));
  pk.y = __builtin_bit_cast(unsigned short, to_bf16(v.y));
  pk.z = __builtin_bit_cast(unsigned short, to_bf16(v.z));
  pk.w = __builtin_bit_cast(unsigned short, to_bf16(v.w));
  *reinterpret_cast<ushort4*>(dst + (size_t)idx * 4) = pk;
}

// dst[(c*rowMul + rowAdd)*dstStride + r] = scale * src[r*C + c]; block (32,8); grid (C/32, R/32)
__global__ void transpose_kernel(const float* __restrict__ src, int C,
                                 bf16* __restrict__ dst, int dstStride, float scale,
                                 int rowMul, int rowAdd) {
  __shared__ float tile[32][33];
  int c0 = blockIdx.x * 32, r0 = blockIdx.y * 32;
  #pragma unroll
  for (int i = 0; i < 32; i += 8) {
    tile[threadIdx.y + i][threadIdx.x] =
        src[(size_t)(r0 + threadIdx.y + i) * C + c0 + threadIdx.x];
  }
  __syncthreads();
  #pragma unroll
  for (int i = 0; i < 32; i += 8) {
    int c = c0 + threadIdx.y + i;
    dst[((size_t)c * rowMul + rowAdd) * dstStride + r0 + threadIdx.x] =
        to_bf16(scale * tile[threadIdx.x][threadIdx.y + i]);
  }
}

// =====================================================================
// GEMM1 (8-phase): U = A @ Bcat^T, fused recurrence epilogue.
// A [8192,1024] bf16; Bcat [4096,1024] bf16, row 2h+0 = Bre^T[h], 2h+1 = Bim^T[h].
// BM=BN=256, BK=64, 8 waves (2M x 4N), per-wave 128x64, acc[8][4].
// LDS: A 2x32KB + B 2x32KB = 128 KiB. Slot swizzle: slot ^= row&7 (both sides).
// Phase map per iteration (tiles T0=2i buf0, T1=2i+1 buf1):
//  ph1: rdA(b0,mh0)+rdB(b0,nh0), stage A(T1)h0   | mma Q(0,0)
//  ph2: rdB(b0,nh1),             stage A(T1)h1   | mma Q(0,1)
//  ph3: rdA(b0,mh1),             stage B(T0+2)h0 | mma Q(1,1)
//  ph4:                          stage B(T0+2)h1 | vmcnt(4) | mma Q(1,0)
//  ph5-8: same on buf1 (stages: A(T0+2)h0/h1, B(T1+2)h0/h1), vmcnt(4) at ph8
// =====================================================================

#define G1_RDA(BUF, MH)                                                        \
  {                                                                            \
    _Pragma("unroll") for (int f = 0; f < 4; ++f) {                            \
      _Pragma("unroll") for (int ks = 0; ks < 2; ++ks) {                       \
        const int row_ = wr + ((MH) * 4 + f) * 16 + m16;                       \
        aF[f][ks] = *reinterpret_cast<const bf16x8*>(                          \
            &Al[BUF][row_ * 64 + (((ks << 2) | q) ^ (row_ & 7)) * 8]);         \
      }                                                                        \
    }                                                                          \
  }

#define G1_RDB(BUF, NH)                                                        \
  {                                                                            \
    _Pragma("unroll") for (int g = 0; g < 2; ++g) {                            \
      _Pragma("unroll") for (int ks = 0; ks < 2; ++ks) {                       \
        const int row_ = wc + ((NH) * 2 + g) * 16 + m16;                       \
        bF[NH][g][ks] = *reinterpret_cast<const bf16x8*>(                      \
            &Bl[BUF][row_ * 64 + (((ks << 2) | q) ^ (row_ & 7)) * 8]);         \
      }                                                                        \
    }                                                                          \
  }

#define G1_MMA(MH, NH)                                                         \
  {                                                                            \
    __builtin_amdgcn_s_setprio(1);                                             \
    _Pragma("unroll") for (int f = 0; f < 4; ++f) {                            \
      _Pragma("unroll") for (int g = 0; g < 2; ++g) {                          \
        _Pragma("unroll") for (int ks = 0; ks < 2; ++ks) {                     \
          acc[(MH) * 4 + f][(NH) * 2 + g] =                                    \
              __builtin_amdgcn_mfma_f32_16x16x32_bf16(                         \
                  aF[f][ks], bF[NH][g][ks], acc[(MH) * 4 + f][(NH) * 2 + g],   \
                  0, 0, 0);                                                    \
        }                                                                      \
      }                                                                        \
    }                                                                          \
    __builtin_amdgcn_s_setprio(0);                                             \
  }

__global__ __launch_bounds__(512, 2) void gemm1_kernel(
    const bf16* __restrict__ A,
    const bf16* __restrict__ Bcat,
    const float* __restrict__ state_re,
    const float* __restrict__ state_im,
    const float* __restrict__ gamma,
    const float* __restrict__ lamRe,
    const float* __restrict__ lamIm,
    float* __restrict__ xre_out,
    float* __restrict__ xim_out,
    bf16* __restrict__ Xcat)
{
  __shared__ __align__(16) bf16 Al[2][256 * 64];   // 64 KiB
  __shared__ __align__(16) bf16 Bl[2][256 * 64];   // 64 KiB

  const int tid   = threadIdx.x;
  const int mBase = blockIdx.y * 256;
  const int nBase = blockIdx.x * 256;
  const int lane  = tid & 63;
  const int wave  = tid >> 6;            // 0..7
  const int wr    = (wave >> 2) * 128;   // 0 or 128
  const int wc    = (wave & 3) * 64;     // 0,64,128,192
  const int m16   = lane & 15;
  const int q     = lane >> 4;

  floatx4 acc[8][4];
  #pragma unroll
  for (int i = 0; i < 8; ++i)
    #pragma unroll
    for (int j = 0; j < 4; ++j) acc[i][j] = floatx4{0.f, 0.f, 0.f, 0.f};

  bf16x8 aF[4][2];
  bf16x8 bF[2][2][2];

  // stage one half-tile (128 rows x 64 cols = 16 KB = 512 thr x 2 x 16B)
  auto stA = [&](int buf_, int kt, int half) {
    #pragma unroll
    for (int p = 0; p < 2; ++p) {
      const int pos = p * 512 + tid;
      const int r   = pos >> 3;
      const int ss  = ((pos & 7) ^ (r & 7)) * 8;
      const bf16* g = &A[(size_t)(mBase + half * 128 + r) * 1024 + kt * 64 + ss];
      async16(g, &Al[buf_][half * 8192 + p * 4096 + wave * 512]);
    }
  };
  auto stB = [&](int buf_, int kt, int half) {
    #pragma unroll
    for (int p = 0; p < 2; ++p) {
      const int pos = p * 512 + tid;
      const int r   = pos >> 3;
      const int ss  = ((pos & 7) ^ (r & 7)) * 8;
      const bf16* g = &Bcat[(size_t)(nBase + half * 128 + r) * 1024 + kt * 64 + ss];
      async16(g, &Bl[buf_][half * 8192 + p * 4096 + wave * 512]);
    }
  };

  // prologue: tile0 full + B(1); A(1) staged at iter0 ph1/2
  stA(0, 0, 0); stA(0, 0, 1); stB(0, 0, 0); stB(0, 0, 1);
  stB(1, 1, 0); stB(1, 1, 1);
  VMW(4);                          // tile0's 8 loads done; B(1)'s 4 in flight
  BAR();

  int kt0 = 0;
  #pragma unroll 1
  for (int it = 0; it < 7; ++it, kt0 += 2) {
    // ph1
    G1_RDA(0, 0); G1_RDB(0, 0); stA(1, kt0 + 1, 0);
    BAR(); LGKM0(); G1_MMA(0, 0); BAR();
    // ph2
    G1_RDB(0, 1); stA(1, kt0 + 1, 1);
    BAR(); LGKM0(); G1_MMA(0, 1); BAR();
    // ph3
    G1_RDA(0, 1); stB(0, kt0 + 2, 0);
    BAR(); LGKM0(); G1_MMA(1, 1); BAR();
    // ph4
    stB(0, kt0 + 2, 1); VMW(4);
    BAR(); G1_MMA(1, 0); BAR();
    // ph5
    G1_RDA(1, 0); G1_RDB(1, 0); stA(0, kt0 + 2, 0);
    BAR(); LGKM0(); G1_MMA(0, 0); BAR();
    // ph6
    G1_RDB(1, 1); stA(0, kt0 + 2, 1);
    BAR(); LGKM0(); G1_MMA(0, 1); BAR();
    // ph7
    G1_RDA(1, 1); stB(1, kt0 + 3, 0);
    BAR(); LGKM0(); G1_MMA(1, 1); BAR();
    // ph8
    stB(1, kt0 + 3, 1); VMW(4);
    BAR(); G1_MMA(1, 0); BAR();
  }
  // peeled last iteration: tiles 14,15; no stages beyond A(15)
  G1_RDA(0, 0); G1_RDB(0, 0); stA(1, 15, 0);
  BAR(); LGKM0(); G1_MMA(0, 0); BAR();
  G1_RDB(0, 1); stA(1, 15, 1);
  BAR(); LGKM0(); G1_MMA(0, 1); BAR();
  G1_RDA(0, 1);
  BAR(); LGKM0(); G1_MMA(1, 1); BAR();
  VMW(0);
  BAR(); G1_MMA(1, 0); BAR();
  G1_RDA(1, 0); G1_RDB(1, 0);
  BAR(); LGKM0(); G1_MMA(0, 0); BAR();
  G1_RDB(1, 1);
  BAR(); LGKM0(); G1_MMA(0, 1); BAR();
  G1_RDA(1, 1);
  BAR(); LGKM0(); G1_MMA(1, 1); BAR();
  G1_MMA(1, 0);

  // fused recurrence epilogue. col nn: even -> u_re of h=nn>>1, odd -> u_im.
  // xr needs only u_re; xi needs only u_im -> no cross-lane exchange.
  #pragma unroll
  for (int j = 0; j < 4; ++j) {
    const int nn = nBase + wc + j * 16 + m16;
    const int h  = nn >> 1;
    const int p  = nn & 1;
    const float gm = gamma[h];
    const float lr = lamRe[h];
    const float li = lamIm[h];
    #pragma unroll
    for (int i = 0; i < 8; ++i) {
      #pragma unroll
      for (int r = 0; r < 4; ++r) {
        const int row = mBase + wr + i * 16 + q * 4 + r;
        const size_t off = (size_t)row * DHID + h;
        const float sr = state_re[off];
        const float si = state_im[off];
        const float u  = gm * acc[i][j][r];
        const float val = p ? (sr * li + si * lr + u)
                            : (sr * lr - si * li + u);
        (p ? xim_out : xre_out)[off] = val;
        Xcat[(size_t)row * (2 * DHID) + h + p * DHID] = to_bf16(val);
      }
    }
  }
}

// =====================================================================
// GEMM2 (8-phase): y = Xcat @ Ccat + D*inputs
// Xcat [8192,4096] bf16; CcatT [1024,4096] bf16.
// BM=128, BN=256 -> grid (4,64)=256 blocks (full GPU). 8 waves, per-wave 64x64,
// acc[4][4]. LDS: A 2x16KB + B 2x64KB... A halves 64x64 (1 load/thr), B 128x64 (2).
// Same phase map; vmcnt(4) at ph4/ph8 (last-2-phase stages = B halves = 4 loads).
// =====================================================================

#define G2_RDA(BUF, MH)                                                        \
  {                                                                            \
    _Pragma("unroll") for (int f = 0; f < 2; ++f) {                            \
      _Pragma("unroll") for (int ks = 0; ks < 2; ++ks) {                       \
        const int row_ = wr + ((MH) * 2 + f) * 16 + m16;                       \
        aF[f][ks] = *reinterpret_cast<const bf16x8*>(                          \
            &Al[BUF][row_ * 64 + (((ks << 2) | q) ^ (row_ & 7)) * 8]);         \
      }                                                                        \
    }                                                                          \
  }

#define G2_RDB(BUF, NH)                                                        \
  {                                                                            \
    _Pragma("unroll") for (int g = 0; g < 2; ++g) {                            \
      _Pragma("unroll") for (int ks = 0; ks < 2; ++ks) {                       \
        const int row_ = wc + ((NH) * 2 + g) * 16 + m16;                       \
        bF[NH][g][ks] = *reinterpret_cast<const bf16x8*>(                      \
            &Bl[BUF][row_ * 64 + (((ks << 2) | q) ^ (row_ & 7)) * 8]);         \
      }                                                                        \
    }                                                                          \
  }

#define G2_MMA(MH, NH)                                                         \
  {                                                                            \
    __builtin_amdgcn_s_setprio(1);                                             \
    _Pragma("unroll") for (int f = 0; f < 2; ++f) {                            \
      _Pragma("unroll") for (int g = 0; g < 2; ++g) {                          \
        _Pragma("unroll") for (int ks = 0; ks < 2; ++ks) {                     \
          acc[(MH) * 2 + f][(NH) * 2 + g] =                                    \
              __builtin_amdgcn_mfma_f32_16x16x32_bf16(                         \
                  aF[f][ks], bF[NH][g][ks], acc[(MH) * 2 + f][(NH) * 2 + g],   \
                  0, 0, 0);                                                    \
        }                                                                      \
      }                                                                        \
    }                                                                          \
    __builtin_amdgcn_s_setprio(0);                                             \
  }

__global__ __launch_bounds__(512, 2) void gemm2_kernel(
    const bf16* __restrict__ Xcat,
    const bf16* __restrict__ CcatT,
    const float* __restrict__ Dvec,
    const float* __restrict__ inputs,
    float* __restrict__ y)
{
  __shared__ __align__(16) bf16 Al[2][128 * 64];   // 32 KiB
  __shared__ __align__(16) bf16 Bl[2][256 * 64];   // 64 KiB

  const int tid   = threadIdx.x;
  const int mBase = blockIdx.y * 128;
  const int nBase = blockIdx.x * 256;
  const int lane  = tid & 63;
  const int wave  = tid >> 6;
  const int wr    = (wave >> 2) * 64;    // 0 or 64
  const int wc    = (wave & 3) * 64;     // 0,64,128,192
  const int m16   = lane & 15;
  const int q     = lane >> 4;

  floatx4 acc[4][4];
  #pragma unroll
  for (int i = 0; i < 4; ++i)
    #pragma unroll
    for (int j = 0; j < 4; ++j) acc[i][j] = floatx4{0.f, 0.f, 0.f, 0.f};

  bf16x8 aF[2][2];
  bf16x8 bF[2][2][2];

  // A half-tile: 64 rows x 64 cols = 8 KB = 1 load/thread
  auto stA = [&](int buf_, int kt, int half) {
    const int r  = tid >> 3;
    const int ss = ((tid & 7) ^ (r & 7)) * 8;
    const bf16* g = &Xcat[(size_t)(mBase + half * 64 + r) * 4096 + kt * 64 + ss];
    async16(g, &Al[buf_][half * 4096 + wave * 512]);
  };
  // B half-tile: 128 rows x 64 cols = 16 KB = 2 loads/thread
  auto stB = [&](int buf_, int kt, int half) {
    #pragma unroll
    for (int p = 0; p < 2; ++p) {
      const int pos = p * 512 + tid;
      const int r   = pos >> 3;
      const int ss  = ((pos & 7) ^ (r & 7)) * 8;
      const bf16* g = &CcatT[(size_t)(nBase + half * 128 + r) * 4096 + kt * 64 + ss];
      async16(g, &Bl[buf_][half * 8192 + p * 4096 + wave * 512]);
    }
  };

  // prologue
  stA(0, 0, 0); stA(0, 0, 1); stB(0, 0, 0); stB(0, 0, 1);
  stB(1, 1, 0); stB(1, 1, 1);
  VMW(4);
  BAR();

  int kt0 = 0;
  #pragma unroll 1
  for (int it = 0; it < 31; ++it, kt0 += 2) {
    // ph1
    G2_RDA(0, 0); G2_RDB(0, 0); stA(1, kt0 + 1, 0);
    BAR(); LGKM0(); G2_MMA(0, 0); BAR();
    // ph2
    G2_RDB(0, 1); stA(1, kt0 + 1, 1);
    BAR(); LGKM0(); G2_MMA(0, 1); BAR();
    // ph3
    G2_RDA(0, 1); stB(0, kt0 + 2, 0);
    BAR(); LGKM0(); G2_MMA(1, 1); BAR();
    // ph4
    stB(0, kt0 + 2, 1); VMW(4);
    BAR(); G2_MMA(1, 0); BAR();
    // ph5
    G2_RDA(1, 0); G2_RDB(1, 0); stA(0, kt0 + 2, 0);
    BAR(); LGKM0(); G2_MMA(0, 0); BAR();
    // ph6
    G2_RDB(1, 1); stA(0, kt0 + 2, 1);
    BAR(); LGKM0(); G2_MMA(0, 1); BAR();
    // ph7
    G2_RDA(1, 1); stB(1, kt0 + 3, 0);
    BAR(); LGKM0(); G2_MMA(1, 1); BAR();
    // ph8
    stB(1, kt0 + 3, 1); VMW(4);
    BAR(); G2_MMA(1, 0); BAR();
  }
  // peeled last iteration: tiles 62,63
  G2_RDA(0, 0); G2_RDB(0, 0); stA(1, 63, 0);
  BAR(); LGKM0(); G2_MMA(0, 0); BAR();
  G2_RDB(0, 1); stA(1, 63, 1);
  BAR(); LGKM0(); G2_MMA(0, 1); BAR();
  G2_RDA(0, 1);
  BAR(); LGKM0(); G2_MMA(1, 1); BAR();
  VMW(0);
  BAR(); G2_MMA(1, 0); BAR();
  G2_RDA(1, 0); G2_RDB(1, 0);
  BAR(); LGKM0(); G2_MMA(0, 0); BAR();
  G2_RDB(1, 1);
  BAR(); LGKM0(); G2_MMA(0, 1); BAR();
  G2_RDA(1, 1);
  BAR(); LGKM0(); G2_MMA(1, 1); BAR();
  G2_MMA(1, 0);

  #pragma unroll
  for (int j = 0; j < 4; ++j) {
    const int n = nBase + wc + j * 16 + m16;
    const float dv = Dvec[n];
    #pragma unroll
    for (int i = 0; i < 4; ++i) {
      #pragma unroll
      for (int r = 0; r < 4; ++r) {
        const int row = mBase + wr + i * 16 + q * 4 + r;
        const size_t idx = (size_t)row * NREC + n;
        y[idx] = acc[i][j][r] + dv * inputs[idx];
      }
    }
  }
}

// ---------------- launch ----------------

extern "C" void kernel_launch(void* const* d_in, const int* in_sizes, int n_in,
                              void* d_out, int out_size, void* d_ws, size_t ws_size,
                              hipStream_t stream) {
  (void)in_sizes; (void)n_in; (void)out_size; (void)ws_size;

  const float* inputs   = (const float*)d_in[0];
  const float* state_re = (const float*)d_in[1];
  const float* state_im = (const float*)d_in[2];
  const float* B_re     = (const float*)d_in[3];
  const float* B_im     = (const float*)d_in[4];
  const float* C_re     = (const float*)d_in[5];
  const float* C_im     = (const float*)d_in[6];
  const float* Dvec     = (const float*)d_in[7];
  const float* nu       = (const float*)d_in[8];
  const float* theta    = (const float*)d_in[9];
  const float* gamma    = (const float*)d_in[10];

  float* out     = (float*)d_out;
  float* y_out   = out;
  float* xre_out = out + (size_t)BATCH * NREC;
  float* xim_out = xre_out + (size_t)BATCH * DHID;

  char* ws = (char*)d_ws;
  bf16*  A1    = (bf16*)(ws + 0);           // 16 MB: inputs bf16 [8192,1024]
  bf16*  Bcat  = (bf16*)(ws + 16777216);    // 8 MB:  [4096,1024], row 2h+p
  bf16*  CcatT = (bf16*)(ws + 25165824);    // 8 MB:  [1024,4096] = [C_re; -C_im]^T
  bf16*  Xcat  = (bf16*)(ws + 33554432);    // 64 MB: [8192,4096]
  float* lamRe = (float*)(ws + 100663296);  // 8 KB
  float* lamIm = (float*)(ws + 100671488);  // 8 KB

  lam_kernel<<<dim3(DHID / 256), dim3(256), 0, stream>>>(nu, theta, lamRe, lamIm);
  convert_kernel<<<dim3((BATCH * NREC) / 1024), dim3(256), 0, stream>>>(inputs, A1);

  dim3 tb(32, 8);
  // Bcat interleaved: row 2h = Bre^T[h], row 2h+1 = Bim^T[h]
  transpose_kernel<<<dim3(2048 / 32, 1024 / 32), tb, 0, stream>>>(B_re, 2048, Bcat, 1024, 1.0f, 2, 0);
  transpose_kernel<<<dim3(2048 / 32, 1024 / 32), tb, 0, stream>>>(B_im, 2048, Bcat, 1024, 1.0f, 2, 1);
  transpose_kernel<<<dim3(1024 / 32, 2048 / 32), tb, 0, stream>>>(C_re, 1024, CcatT, 4096, 1.0f, 1, 0);
  transpose_kernel<<<dim3(1024 / 32, 2048 / 32), tb, 0, stream>>>(C_im, 1024, CcatT + 2048, 4096, -1.0f, 1, 0);

  gemm1_kernel<<<dim3(DHID * 2 / 256, BATCH / 256), dim3(512), 0, stream>>>(
      A1, Bcat, state_re, state_im, gamma, lamRe, lamIm, xre_out, xim_out, Xcat);

  gemm2_kernel<<<dim3(NREC / 256, BATCH / 128), dim3(512), 0, stream>>>(
      Xcat, CcatT, Dvec, inputs, y_out);
}

// Round 5
// 554.707 us; speedup vs baseline: 1.3508x; 1.3508x over previous
//
#include <hip/hip_runtime.h>
#include <hip/hip_bf16.h>

typedef __bf16 bf16;
typedef __attribute__((ext_vector_type(8))) __bf16 bf16x8;
typedef __attribute__((ext_vector_type(4))) float floatx4;

#define BATCH 8192
#define NREC  1024
#define DHID  2048

#define GLOBAL_AS __attribute__((address_space(1)))
#define LDS_AS    __attribute__((address_space(3)))

__device__ __forceinline__ bf16 to_bf16(float f) { return (bf16)f; }

// async global->LDS, 16 bytes per lane; LDS dest = wave-uniform base + lane*16
__device__ __forceinline__ void async16(const void* g, void* l) {
  __builtin_amdgcn_global_load_lds((const GLOBAL_AS unsigned int*)g,
                                   (LDS_AS unsigned int*)l, 16, 0, 0);
}

// Swizzled LDS fragment read: LDS tile is [128][32] bf16 (64 B rows, 4x 16B slots).
// Stored with slot s holding global slot s ^ ((row>>1)&3); read applies same XOR.
// (verified round 1: SQ_LDS_BANK_CONFLICT -> 0)
__device__ __forceinline__ bf16x8 ldsFrag(const bf16* buf, int row, int q) {
  const int s = (q ^ ((row >> 1) & 3)) * 8;
  return *reinterpret_cast<const bf16x8*>(&buf[row * 32 + s]);
}

// ---------------- merged prep kernel ----------------
// One launch replaces lam + convert + 4 transposes (kills ~5 inter-kernel gaps).
// Block map (256 threads each):
//   [0,      8192)  convert inputs f32 -> A1 bf16 (4 elem/thread)
//   [8192,  10240)  transpose B_re [1024,2048] -> BreT  [2048,1024]
//   [10240, 12288)  transpose B_im [1024,2048] -> BimT  [2048,1024]
//   [12288, 14336)  transpose C_re [2048,1024] -> CcatT cols [0,2048)    (+1)
//   [14336, 16384)  transpose C_im [2048,1024] -> CcatT cols [2048,4096) (-1)
//   [16384, 16392)  lam
__global__ __launch_bounds__(256) void prep_kernel(
    const float* __restrict__ inputs, bf16* __restrict__ A1,
    const float* __restrict__ B_re, const float* __restrict__ B_im,
    bf16* __restrict__ BreT, bf16* __restrict__ BimT,
    const float* __restrict__ C_re, const float* __restrict__ C_im,
    bf16* __restrict__ CcatT,
    const float* __restrict__ nu, const float* __restrict__ theta,
    float* __restrict__ lamRe, float* __restrict__ lamIm)
{
  __shared__ float tile[32][33];
  const int b   = blockIdx.x;
  const int tid = threadIdx.x;

  if (b < 8192) {
    // convert
    const int idx = b * 256 + tid;
    float4 v = reinterpret_cast<const float4*>(inputs)[idx];
    ushort4 pk;
    pk.x = __builtin_bit_cast(unsigned short, to_bf16(v.x));
    pk.y = __builtin_bit_cast(unsigned short, to_bf16(v.y));
    pk.z = __builtin_bit_cast(unsigned short, to_bf16(v.z));
    pk.w = __builtin_bit_cast(unsigned short, to_bf16(v.w));
    *reinterpret_cast<ushort4*>(A1 + (size_t)idx * 4) = pk;
    return;
  }
  if (b < 16384) {
    // transpose: pick task.  NOTE: C_im dst is a COLUMN offset (+2048 elements)
    // into the [1024,4096] CcatT matrix, not a row offset (round-4 bug).
    const float* src; bf16* dst; int C, dstStride; float scale; int t;
    if (b < 10240)      { t = b - 8192;  src = B_re; dst = BreT;         C = 2048; dstStride = 1024; scale =  1.0f; }
    else if (b < 12288) { t = b - 10240; src = B_im; dst = BimT;         C = 2048; dstStride = 1024; scale =  1.0f; }
    else if (b < 14336) { t = b - 12288; src = C_re; dst = CcatT;        C = 1024; dstStride = 4096; scale =  1.0f; }
    else                { t = b - 14336; src = C_im; dst = CcatT + 2048; C = 1024; dstStride = 4096; scale = -1.0f; }
    const int gx = C / 32;               // tiles along columns of src
    const int bx = t % gx, by = t / gx;
    const int c0 = bx * 32, r0 = by * 32;
    const int tx = tid & 31, ty = tid >> 5;   // (32,8)
    #pragma unroll
    for (int i = 0; i < 32; i += 8) {
      tile[ty + i][tx] = src[(size_t)(r0 + ty + i) * C + c0 + tx];
    }
    __syncthreads();
    #pragma unroll
    for (int i = 0; i < 32; i += 8) {
      const int c = c0 + ty + i;
      dst[(size_t)c * dstStride + r0 + tx] = to_bf16(scale * tile[tx][ty + i]);
    }
    return;
  }
  // lam
  const int h = (b - 16384) * 256 + tid;
  if (h < DHID) {
    float tt = expf(-expf(nu[h]));
    lamRe[h] = tt * cosf(theta[h]);
    lamIm[h] = tt * sinf(theta[h]);
  }
}

// ---------------- GEMM1: U_re/U_im = inputs @ B_{re,im}, fused recurrence epilogue ----
// Round-2 structure (verified 194 us) + XCD band-grouped block swizzle:
// XCD j (= dispatch_id % 8) owns contiguous row-bands, so the 16 column-blocks
// sharing an A band-slice hit the same per-XCD L2 instead of 8 incoherent ones.

__global__ __launch_bounds__(512, 3) void gemm1_kernel(
    const bf16* __restrict__ A,
    const bf16* __restrict__ BreT,
    const bf16* __restrict__ BimT,
    const float* __restrict__ state_re,
    const float* __restrict__ state_im,
    const float* __restrict__ gamma,
    const float* __restrict__ lamRe,
    const float* __restrict__ lamIm,
    float* __restrict__ xre_out,
    float* __restrict__ xim_out,
    bf16* __restrict__ Xcat)
{
  __shared__ __align__(16) bf16 Alds[2][128 * 32];
  __shared__ __align__(16) bf16 BreLds[2][128 * 32];
  __shared__ __align__(16) bf16 BimLds[2][128 * 32];

  const int tid = threadIdx.x;
  // band-grouped XCD swizzle (nwg = 16*64 = 1024, divisible by 8; bijective)
  const int d       = blockIdx.x + blockIdx.y * gridDim.x;
  const int cpx     = (gridDim.x * gridDim.y) >> 3;
  const int logical = (d & 7) * cpx + (d >> 3);
  const int mBase = (logical / gridDim.x) * 128;
  const int hBase = (logical % gridDim.x) * 128;

  const int lane  = tid & 63;
  const int wave  = tid >> 6;        // 0..7
  const int wr    = (wave >> 2) * 64; // 0 or 64
  const int wc    = (wave & 3) * 32;  // 0,32,64,96
  const int m16   = lane & 15;
  const int q     = lane >> 4;

  floatx4 zero = {0.f, 0.f, 0.f, 0.f};
  floatx4 accRe[4][2], accIm[4][2];
  #pragma unroll
  for (int i = 0; i < 4; ++i)
    #pragma unroll
    for (int j = 0; j < 2; ++j) { accRe[i][j] = zero; accIm[i][j] = zero; }

  const int row0 = tid >> 2;          // 0..127
  const int ss   = ((tid & 3) ^ ((row0 >> 1) & 3)) * 8;  // pre-swizzled source slot
  const int wbase = wave * 512;       // wave-uniform LDS base (elements)

  auto stage = [&](int buf, int kt) {
    const size_t aoff = (size_t)(mBase + row0) * 1024 + kt + ss;
    const size_t boff = (size_t)(hBase + row0) * 1024 + kt + ss;
    async16(&A[aoff],    &Alds[buf][wbase]);
    async16(&BreT[boff], &BreLds[buf][wbase]);
    async16(&BimT[boff], &BimLds[buf][wbase]);
  };

  auto computeTile = [&](int buf) {
    bf16x8 aF[4], brF[2], biF[2];
    #pragma unroll
    for (int i = 0; i < 4; ++i)
      aF[i] = ldsFrag(Alds[buf], wr + i * 16 + m16, q);
    #pragma unroll
    for (int j = 0; j < 2; ++j) {
      brF[j] = ldsFrag(BreLds[buf], wc + j * 16 + m16, q);
      biF[j] = ldsFrag(BimLds[buf], wc + j * 16 + m16, q);
    }
    #pragma unroll
    for (int i = 0; i < 4; ++i)
      #pragma unroll
      for (int j = 0; j < 2; ++j) {
        accRe[i][j] = __builtin_amdgcn_mfma_f32_16x16x32_bf16(aF[i], brF[j], accRe[i][j], 0, 0, 0);
        accIm[i][j] = __builtin_amdgcn_mfma_f32_16x16x32_bf16(aF[i], biF[j], accIm[i][j], 0, 0, 0);
      }
  };

  stage(0, 0);
  __syncthreads();                  // buf0 ready
  int cur = 0;
  for (int kt = 32; kt < 1024; kt += 32) {
    stage(cur ^ 1, kt);             // next-tile loads in flight during compute
    computeTile(cur);
    __syncthreads();                // drains vmcnt(0): next tile ready
    cur ^= 1;
  }
  computeTile(cur);                 // last tile, no prefetch

  // fused elementwise recurrence epilogue
  #pragma unroll
  for (int j = 0; j < 2; ++j) {
    const int h  = hBase + wc + j * 16 + m16;
    const float g  = gamma[h];
    const float lr = lamRe[h];
    const float li = lamIm[h];
    #pragma unroll
    for (int i = 0; i < 4; ++i) {
      #pragma unroll
      for (int r = 0; r < 4; ++r) {
        const int row = mBase + wr + i * 16 + q * 4 + r;
        const size_t off = (size_t)row * DHID + h;
        const float ur = g * accRe[i][j][r];
        const float ui = g * accIm[i][j][r];
        const float sr = state_re[off];
        const float si = state_im[off];
        const float xr = sr * lr - si * li + ur;
        const float xi = sr * li + si * lr + ui;
        xre_out[off] = xr;
        xim_out[off] = xi;
        const size_t xoff = (size_t)row * (2 * DHID) + h;
        Xcat[xoff]        = to_bf16(xr);
        Xcat[xoff + DHID] = to_bf16(xi);
      }
    }
  }
}

// ---------------- GEMM2: y = Xcat @ Ccat + D*inputs ----------------
// Xcat [8192,4096] bf16; CcatT [1024,4096] bf16 ([n][k], rows n, k over 2H)
// Round-2 structure + XCD band-grouped swizzle (nwg = 8*64 = 512; bijective).

__global__ __launch_bounds__(512, 4) void gemm2_kernel(
    const bf16* __restrict__ Xcat,
    const bf16* __restrict__ CcatT,
    const float* __restrict__ Dvec,
    const float* __restrict__ inputs,
    float* __restrict__ y)
{
  __shared__ __align__(16) bf16 Alds[2][128 * 32];
  __shared__ __align__(16) bf16 Blds[2][128 * 32];

  const int tid = threadIdx.x;
  const int d       = blockIdx.x + blockIdx.y * gridDim.x;
  const int cpx     = (gridDim.x * gridDim.y) >> 3;
  const int logical = (d & 7) * cpx + (d >> 3);
  const int mBase = (logical / gridDim.x) * 128;
  const int nBase = (logical % gridDim.x) * 128;

  const int lane  = tid & 63;
  const int wave  = tid >> 6;
  const int wr    = (wave >> 2) * 64;
  const int wc    = (wave & 3) * 32;
  const int m16   = lane & 15;
  const int q     = lane >> 4;

  floatx4 zero = {0.f, 0.f, 0.f, 0.f};
  floatx4 acc[4][2];
  #pragma unroll
  for (int i = 0; i < 4; ++i)
    #pragma unroll
    for (int j = 0; j < 2; ++j) acc[i][j] = zero;

  const int row0 = tid >> 2;
  const int ss   = ((tid & 3) ^ ((row0 >> 1) & 3)) * 8;
  const int wbase = wave * 512;

  auto stage = [&](int buf, int kt) {
    const size_t aoff = (size_t)(mBase + row0) * 4096 + kt + ss;
    const size_t boff = (size_t)(nBase + row0) * 4096 + kt + ss;
    async16(&Xcat[aoff],  &Alds[buf][wbase]);
    async16(&CcatT[boff], &Blds[buf][wbase]);
  };

  auto computeTile = [&](int buf) {
    bf16x8 aF[4], bF[2];
    #pragma unroll
    for (int i = 0; i < 4; ++i)
      aF[i] = ldsFrag(Alds[buf], wr + i * 16 + m16, q);
    #pragma unroll
    for (int j = 0; j < 2; ++j)
      bF[j] = ldsFrag(Blds[buf], wc + j * 16 + m16, q);
    #pragma unroll
    for (int i = 0; i < 4; ++i)
      #pragma unroll
      for (int j = 0; j < 2; ++j)
        acc[i][j] = __builtin_amdgcn_mfma_f32_16x16x32_bf16(aF[i], bF[j], acc[i][j], 0, 0, 0);
  };

  stage(0, 0);
  __syncthreads();
  int cur = 0;
  for (int kt = 32; kt < 4096; kt += 32) {
    stage(cur ^ 1, kt);
    computeTile(cur);
    __syncthreads();
    cur ^= 1;
  }
  computeTile(cur);

  #pragma unroll
  for (int j = 0; j < 2; ++j) {
    const int n = nBase + wc + j * 16 + m16;
    const float dv = Dvec[n];
    #pragma unroll
    for (int i = 0; i < 4; ++i) {
      #pragma unroll
      for (int r = 0; r < 4; ++r) {
        const int row = mBase + wr + i * 16 + q * 4 + r;
        const size_t idx = (size_t)row * NREC + n;
        y[idx] = acc[i][j][r] + dv * inputs[idx];
      }
    }
  }
}

// ---------------- launch ----------------

extern "C" void kernel_launch(void* const* d_in, const int* in_sizes, int n_in,
                              void* d_out, int out_size, void* d_ws, size_t ws_size,
                              hipStream_t stream) {
  (void)in_sizes; (void)n_in; (void)out_size; (void)ws_size;

  const float* inputs   = (const float*)d_in[0];
  const float* state_re = (const float*)d_in[1];
  const float* state_im = (const float*)d_in[2];
  const float* B_re     = (const float*)d_in[3];
  const float* B_im     = (const float*)d_in[4];
  const float* C_re     = (const float*)d_in[5];
  const float* C_im     = (const float*)d_in[6];
  const float* Dvec     = (const float*)d_in[7];
  const float* nu       = (const float*)d_in[8];
  const float* theta    = (const float*)d_in[9];
  const float* gamma    = (const float*)d_in[10];

  float* out     = (float*)d_out;
  float* y_out   = out;
  float* xre_out = out + (size_t)BATCH * NREC;
  float* xim_out = xre_out + (size_t)BATCH * DHID;

  char* ws = (char*)d_ws;
  bf16*  A1    = (bf16*)(ws + 0);           // 16 MB: inputs bf16 [8192,1024]
  bf16*  BreT  = (bf16*)(ws + 16777216);    // 4 MB:  [2048,1024]
  bf16*  BimT  = (bf16*)(ws + 20971520);    // 4 MB
  bf16*  CcatT = (bf16*)(ws + 25165824);    // 8 MB:  [1024,4096] = [C_re | -C_im]^T
  bf16*  Xcat  = (bf16*)(ws + 33554432);    // 64 MB: [8192,4096]
  float* lamRe = (float*)(ws + 100663296);  // 8 KB
  float* lamIm = (float*)(ws + 100671488);  // 8 KB

  prep_kernel<<<dim3(16392), dim3(256), 0, stream>>>(
      inputs, A1, B_re, B_im, BreT, BimT, C_re, C_im, CcatT,
      nu, theta, lamRe, lamIm);

  gemm1_kernel<<<dim3(DHID / 128, BATCH / 128), dim3(512), 0, stream>>>(
      A1, BreT, BimT, state_re, state_im, gamma, lamRe, lamIm, xre_out, xim_out, Xcat);

  gemm2_kernel<<<dim3(NREC / 128, BATCH / 128), dim3(512), 0, stream>>>(
      Xcat, CcatT, Dvec, inputs, y_out);
}